// Round 1
// baseline (763.693 us; speedup 1.0000x reference)
//
#include <hip/hip_runtime.h>
#include <cstdint>
#include <cstddef>

typedef unsigned short ushort_t;
typedef unsigned int u32;
typedef __attribute__((ext_vector_type(8))) short bf16x8;
typedef __attribute__((ext_vector_type(4))) float f32x4;
typedef __attribute__((ext_vector_type(4))) unsigned short u16x4;

#define DEV static __device__ __forceinline__

// ---- bf16 helpers (RNE) ----
DEV ushort_t f2bf(float f) {
  u32 x = __float_as_uint(f);
  x += 0x7fff + ((x >> 16) & 1);
  return (ushort_t)(x >> 16);
}
DEV float bf2f(ushort_t u) { return __uint_as_float(((u32)u) << 16); }

// Problem dims: B=8, S=512, D=1024, H=16, DH=64, M = B*S = 4096.

// ---------------------------------------------------------------------------
// Input f32 -> bf16 conversion (title & content), 4 floats/thread each.
__global__ __launch_bounds__(256) void cvt_inputs(
    const float* __restrict__ xa, const float* __restrict__ xb,
    ushort_t* __restrict__ oa, ushort_t* __restrict__ ob) {
  int i = blockIdx.x * 256 + threadIdx.x;  // f32x4 index, 1048576 total
  f32x4 va = ((const f32x4*)xa)[i];
  f32x4 vb = ((const f32x4*)xb)[i];
  u16x4 ua, ub;
#pragma unroll
  for (int j = 0; j < 4; ++j) { ua[j] = f2bf(va[j]); ub[j] = f2bf(vb[j]); }
  ((u16x4*)oa)[i] = ua;
  ((u16x4*)ob)[i] = ub;
}

// ---------------------------------------------------------------------------
// W [K][N] f32  ->  Wt [N][K] bf16  (32x32 LDS tile transpose)
__global__ __launch_bounds__(256) void transpose_cvt(
    const float* __restrict__ src, ushort_t* __restrict__ dst, int K, int N) {
  __shared__ float t[32][33];
  int n0 = blockIdx.x << 5, k0 = blockIdx.y << 5;
  int tx = threadIdx.x & 31, ty = threadIdx.x >> 5;  // 32 x 8
#pragma unroll
  for (int i = 0; i < 4; ++i)
    t[ty + i * 8][tx] = src[(size_t)(k0 + ty + i * 8) * N + n0 + tx];
  __syncthreads();
#pragma unroll
  for (int i = 0; i < 4; ++i)
    dst[(size_t)(n0 + ty + i * 8) * K + k0 + tx] = f2bf(t[tx][ty + i * 8]);
}

// ---------------------------------------------------------------------------
// Generic bf16 MFMA GEMM: C[m][n] = sum_k A[m][k] * Bt[n][k] + bias[n]
// M=4096, N=1024 fixed; K = Ktot; A = A1 for k<KA1 else A2 (virtual concat).
// 128x128 tile, BK=64, 4 waves (2x2), wave tile 64x64 = 4x4 frags 16x16x32.
enum { EPI_QKV = 0, EPI_VT = 1, EPI_BF16 = 2, EPI_F32 = 3 };

template <int EPI>
__global__ __launch_bounds__(256, 2) void gemm_kernel(
    const ushort_t* __restrict__ A1, const ushort_t* __restrict__ A2, int KA1,
    const ushort_t* __restrict__ Bt, const float* __restrict__ bias,
    void* __restrict__ Cout, int Ktot) {
  // padded stride 72 halfs = 144B (16B-aligned, 2-way-max bank aliasing)
  __shared__ ushort_t As[128 * 72];
  __shared__ ushort_t Bs[128 * 72];
  const int tid = threadIdx.x;
  const int w = tid >> 6, lane = tid & 63;
  const int g = lane >> 4, c = lane & 15;
  const int wm = (w >> 1) << 6, wn = (w & 1) << 6;
  const int m0 = blockIdx.x << 7, n0 = blockIdx.y << 7;

  f32x4 acc[4][4];
#pragma unroll
  for (int i = 0; i < 4; ++i)
#pragma unroll
    for (int j = 0; j < 4; ++j) acc[i][j] = f32x4{0.f, 0.f, 0.f, 0.f};

  for (int k0 = 0; k0 < Ktot; k0 += 64) {
    const ushort_t* Ak; int kk, lda;
    if (k0 < KA1) { Ak = A1; kk = k0; lda = KA1; }
    else          { Ak = A2; kk = k0 - KA1; lda = Ktot - KA1; }
#pragma unroll
    for (int i = 0; i < 4; ++i) {
      int ch = tid + (i << 8);       // 1024 chunks of 16B per operand tile
      int row = ch >> 3, kc = ch & 7;
      bf16x8 va = *(const bf16x8*)(Ak + (size_t)(m0 + row) * lda + kk + (kc << 3));
      *(bf16x8*)&As[row * 72 + (kc << 3)] = va;
      bf16x8 vb = *(const bf16x8*)(Bt + (size_t)(n0 + row) * Ktot + k0 + (kc << 3));
      *(bf16x8*)&Bs[row * 72 + (kc << 3)] = vb;
    }
    __syncthreads();
#pragma unroll
    for (int ks = 0; ks < 2; ++ks) {
      bf16x8 af[4], bfr[4];
#pragma unroll
      for (int mi = 0; mi < 4; ++mi)
        af[mi] = *(const bf16x8*)&As[(wm + mi * 16 + c) * 72 + ks * 32 + (g << 3)];
#pragma unroll
      for (int ni = 0; ni < 4; ++ni)
        bfr[ni] = *(const bf16x8*)&Bs[(wn + ni * 16 + c) * 72 + ks * 32 + (g << 3)];
#pragma unroll
      for (int mi = 0; mi < 4; ++mi)
#pragma unroll
        for (int ni = 0; ni < 4; ++ni)
          acc[mi][ni] = __builtin_amdgcn_mfma_f32_16x16x32_bf16(
              af[mi], bfr[ni], acc[mi][ni], 0, 0, 0);
    }
    __syncthreads();
  }

  // Epilogue. D frag layout: row = 4*(lane>>4)+reg (M dim), col = lane&15 (N dim).
#pragma unroll
  for (int ni = 0; ni < 4; ++ni) {
    const int n = n0 + wn + ni * 16 + c;
    const float bv = bias[n];
#pragma unroll
    for (int mi = 0; mi < 4; ++mi) {
      const int mb = m0 + wm + mi * 16 + (g << 2);
      f32x4 a = acc[mi][ni];
      if (EPI == EPI_VT) {
        // Vt[((b*16+h)*64 + d)*512 + s], 4 consecutive s -> one 8B store
        int b = mb >> 9, s = mb & 511, h = n >> 6, d = n & 63;
        u16x4 o;
#pragma unroll
        for (int r = 0; r < 4; ++r) o[r] = f2bf(a[r] + bv);
        *(u16x4*)((ushort_t*)Cout + (((size_t)((b * 16 + h) * 64 + d)) << 9) + s) = o;
      } else {
#pragma unroll
        for (int r = 0; r < 4; ++r) {
          int m = mb + r;
          float v = a[r] + bv;
          if (EPI == EPI_QKV) {
            int b = m >> 9, s = m & 511, h = n >> 6, d = n & 63;
            ((ushort_t*)Cout)[(((size_t)(b * 16 + h) * 512 + s) << 6) + d] = f2bf(v);
          } else if (EPI == EPI_BF16) {
            ((ushort_t*)Cout)[(size_t)m * 1024 + n] = f2bf(v);
          } else {  // EPI_F32
            ((float*)Cout)[(size_t)m * 1024 + n] = v;
          }
        }
      }
    }
  }
}

// ---------------------------------------------------------------------------
// Attention per (dir fixed per call). Grid: bh(128) x qtile(8). 4 waves,
// wave owns 16 q rows. Swapped scores^T = mfma(K, Q) -> lane owns column q.
// KL term skipped (softmax shift-invariant). PV = mfma(V^T, P).
__global__ __launch_bounds__(256, 2) void attn_kernel(
    const ushort_t* __restrict__ Q, const ushort_t* __restrict__ Kp,
    const ushort_t* __restrict__ Vt, ushort_t* __restrict__ ctx) {
  const int tid = threadIdx.x, w = tid >> 6, lane = tid & 63;
  const int g = lane >> 4, c = lane & 15;
  const int bh = blockIdx.x >> 3, qt = blockIdx.x & 7;
  const int q0 = (qt << 6) + (w << 4);
  const ushort_t* Qb = Q + ((size_t)bh << 15);   // 512*64
  const ushort_t* Kb = Kp + ((size_t)bh << 15);
  const ushort_t* Vb = Vt + ((size_t)bh << 15);  // [64][512]

  bf16x8 qf0 = *(const bf16x8*)&Qb[((q0 + c) << 6) + (g << 3)];
  bf16x8 qf1 = *(const bf16x8*)&Qb[((q0 + c) << 6) + 32 + (g << 3)];

  f32x4 s[32];           // scores^T: rows kk = 16t + 4g + reg, col q = q0 + c
  float mx = -1e30f;
#pragma unroll
  for (int t = 0; t < 32; ++t) {
    bf16x8 a0 = *(const bf16x8*)&Kb[(((t << 4) + c) << 6) + (g << 3)];
    bf16x8 a1 = *(const bf16x8*)&Kb[(((t << 4) + c) << 6) + 32 + (g << 3)];
    f32x4 z = {0.f, 0.f, 0.f, 0.f};
    z = __builtin_amdgcn_mfma_f32_16x16x32_bf16(a0, qf0, z, 0, 0, 0);
    z = __builtin_amdgcn_mfma_f32_16x16x32_bf16(a1, qf1, z, 0, 0, 0);
    s[t] = z;
    mx = fmaxf(mx, fmaxf(fmaxf(z[0], z[1]), fmaxf(z[2], z[3])));
  }
  // column (= softmax row) reduce across the 4 g-lane-groups
  mx = fmaxf(mx, __shfl_xor(mx, 16, 64));
  mx = fmaxf(mx, __shfl_xor(mx, 32, 64));
  const float SC = 0.125f;  // 1/sqrt(64)
  float sum = 0.f;
#pragma unroll
  for (int t = 0; t < 32; ++t) {
#pragma unroll
    for (int r = 0; r < 4; ++r) {
      float p = __expf((s[t][r] - mx) * SC);
      s[t][r] = p;
      sum += p;
    }
  }
  sum += __shfl_xor(sum, 16, 64);
  sum += __shfl_xor(sum, 32, 64);
  const float inv = 1.0f / sum;

  f32x4 pacc[4];
#pragma unroll
  for (int dt = 0; dt < 4; ++dt) pacc[dt] = f32x4{0.f, 0.f, 0.f, 0.f};
  const int s1 = ((g & 1) << 5) + c;  // src lane A (g'=2*(g&1))
  const int s2 = s1 + 16;             // src lane B (g'=2*(g&1)+1)
  const bool hi = (g >> 1) != 0;      // k 16..31 -> odd score tile
#pragma unroll
  for (int t2 = 0; t2 < 16; ++t2) {
    // pack the two 16-row tiles covering k = 32*t2 .. +31 into bf16 pairs
    u32 A0 = ((u32)f2bf(s[2 * t2][1]) << 16) | f2bf(s[2 * t2][0]);
    u32 A1p = ((u32)f2bf(s[2 * t2][3]) << 16) | f2bf(s[2 * t2][2]);
    u32 B0 = ((u32)f2bf(s[2 * t2 + 1][1]) << 16) | f2bf(s[2 * t2 + 1][0]);
    u32 B1 = ((u32)f2bf(s[2 * t2 + 1][3]) << 16) | f2bf(s[2 * t2 + 1][2]);
    u32 xA0 = (u32)__shfl((int)A0, s1, 64), xA1 = (u32)__shfl((int)A1p, s1, 64);
    u32 xB0 = (u32)__shfl((int)B0, s1, 64), xB1 = (u32)__shfl((int)B1, s1, 64);
    u32 yA0 = (u32)__shfl((int)A0, s2, 64), yA1 = (u32)__shfl((int)A1p, s2, 64);
    u32 yB0 = (u32)__shfl((int)B0, s2, 64), yB1 = (u32)__shfl((int)B1, s2, 64);
    union { bf16x8 v; u32 wd[4]; } pb;
    pb.wd[0] = hi ? xB0 : xA0;
    pb.wd[1] = hi ? xB1 : xA1;
    pb.wd[2] = hi ? yB0 : yA0;
    pb.wd[3] = hi ? yB1 : yA1;
#pragma unroll
    for (int dt = 0; dt < 4; ++dt) {
      bf16x8 av = *(const bf16x8*)&Vb[(((dt << 4) + c) << 9) + (t2 << 5) + (g << 3)];
      pacc[dt] = __builtin_amdgcn_mfma_f32_16x16x32_bf16(av, pb.v, pacc[dt], 0, 0, 0);
    }
  }
  // ctx^T frag: rows d = dt*16 + 4g + reg, col q = q0+c. Normalize by 1/sum.
  const int b = bh >> 4, h = bh & 15;
  size_t obase = ((size_t)b * 512 + q0 + c) * 1024 + (h << 6);
#pragma unroll
  for (int dt = 0; dt < 4; ++dt) {
    u16x4 o;
#pragma unroll
    for (int r = 0; r < 4; ++r) o[r] = f2bf(pacc[dt][r] * inv);
    *(u16x4*)&ctx[obase + (dt << 4) + (g << 2)] = o;
  }
}

// ---------------------------------------------------------------------------
// gate = sigmoid(logit); f = gate*x + (1-gate)*attn; out = LayerNorm(f)
__global__ __launch_bounds__(256) void fuse_ln(
    const float* __restrict__ xt, const float* __restrict__ xc,
    const ushort_t* __restrict__ a0, const ushort_t* __restrict__ a1,
    const float* __restrict__ g0, const float* __restrict__ g1,
    const float* __restrict__ lng, const float* __restrict__ lnb,
    float* __restrict__ out) {
  const int row = blockIdx.x, dir = row >> 12, r = row & 4095;
  const float* x = (dir ? xc : xt) + ((size_t)r << 10);
  const ushort_t* a = (dir ? a1 : a0) + ((size_t)r << 10);
  const float* gl = (dir ? g1 : g0) + ((size_t)r << 10);
  float* o = out + ((size_t)dir << 22) + ((size_t)r << 10);
  const int t = threadIdx.x, w = t >> 6, lane = t & 63;
  f32x4 xv = ((const f32x4*)x)[t];
  u16x4 av = ((const u16x4*)a)[t];
  f32x4 gv = ((const f32x4*)gl)[t];
  f32x4 f;
  float sm = 0.f, sq = 0.f;
#pragma unroll
  for (int j = 0; j < 4; ++j) {
    float gate = 1.f / (1.f + __expf(-gv[j]));
    float fv = gate * xv[j] + (1.f - gate) * bf2f(av[j]);
    f[j] = fv; sm += fv; sq += fv * fv;
  }
#pragma unroll
  for (int d = 1; d < 64; d <<= 1) {
    sm += __shfl_xor(sm, d, 64);
    sq += __shfl_xor(sq, d, 64);
  }
  __shared__ float ps[8];
  if (lane == 0) { ps[w] = sm; ps[4 + w] = sq; }
  __syncthreads();
  sm = ps[0] + ps[1] + ps[2] + ps[3];
  sq = ps[4] + ps[5] + ps[6] + ps[7];
  const float mu = sm * (1.f / 1024.f);
  const float var = sq * (1.f / 1024.f) - mu * mu;
  const float rstd = rsqrtf(var + 1e-5f);
  f32x4 lg = ((const f32x4*)lng)[t], lb = ((const f32x4*)lnb)[t];
  f32x4 ov;
#pragma unroll
  for (int j = 0; j < 4; ++j) ov[j] = lg[j] * (f[j] - mu) * rstd + lb[j];
  ((f32x4*)o)[t] = ov;
}

// ---------------------------------------------------------------------------
extern "C" void kernel_launch(void* const* d_in, const int* in_sizes, int n_in,
                              void* d_out, int out_size, void* d_ws, size_t ws_size,
                              hipStream_t stream) {
  (void)in_sizes; (void)n_in; (void)out_size; (void)ws_size;
  const float* title = (const float*)d_in[0];
  const float* content = (const float*)d_in[1];

  char* ws = (char*)d_ws;
  const size_t MB = 1u << 20;
  ushort_t* Xt = (ushort_t*)(ws + 0 * MB);       // 8 MB
  ushort_t* Xc = (ushort_t*)(ws + 8 * MB);       // 8 MB
  ushort_t* WT[8];
  for (int i = 0; i < 8; ++i) WT[i] = (ushort_t*)(ws + 16 * MB + i * 2 * MB);  // 16 MB
  ushort_t* WgT = (ushort_t*)(ws + 32 * MB);     // 4 MB [1024][2048]
  ushort_t* Qb  = (ushort_t*)(ws + 36 * MB);     // 8 MB [B][H][S][DH]
  ushort_t* Kb  = (ushort_t*)(ws + 44 * MB);     // 8 MB
  ushort_t* Vtb = (ushort_t*)(ws + 52 * MB);     // 8 MB [B][H][DH][S]
  ushort_t* ctx = (ushort_t*)(ws + 60 * MB);     // 8 MB
  ushort_t* ao0 = (ushort_t*)(ws + 68 * MB);     // 8 MB  t2c
  ushort_t* ao1 = (ushort_t*)(ws + 76 * MB);     // 8 MB  c2t
  float* gl0 = (float*)(ws + 84 * MB);           // 16 MB
  float* gl1 = (float*)(ws + 100 * MB);          // 16 MB  (total 116 MB)

  cvt_inputs<<<4096, 256, 0, stream>>>(title, content, Xt, Xc);
  for (int i = 0; i < 8; ++i)
    transpose_cvt<<<dim3(32, 32), 256, 0, stream>>>((const float*)d_in[2 + 2 * i], WT[i], 1024, 1024);
  transpose_cvt<<<dim3(32, 64), 256, 0, stream>>>((const float*)d_in[18], WgT, 2048, 1024);

  const dim3 gg(32, 8);
  // dir 0: t2c = DAA(q=content, k/v=title, t2c weights)
  gemm_kernel<EPI_QKV><<<gg, 256, 0, stream>>>(Xc, nullptr, 1024, WT[0], (const float*)d_in[3], Qb, 1024);
  gemm_kernel<EPI_QKV><<<gg, 256, 0, stream>>>(Xt, nullptr, 1024, WT[1], (const float*)d_in[5], Kb, 1024);
  gemm_kernel<EPI_VT ><<<gg, 256, 0, stream>>>(Xt, nullptr, 1024, WT[2], (const float*)d_in[7], Vtb, 1024);
  attn_kernel<<<1024, 256, 0, stream>>>(Qb, Kb, Vtb, ctx);
  gemm_kernel<EPI_BF16><<<gg, 256, 0, stream>>>(ctx, nullptr, 1024, WT[3], (const float*)d_in[9], ao0, 1024);
  gemm_kernel<EPI_F32><<<gg, 256, 0, stream>>>(Xt, ao0, 1024, WgT, (const float*)d_in[19], gl0, 2048);

  // dir 1: c2t = DAA(q=title, k/v=content, c2t weights)
  gemm_kernel<EPI_QKV><<<gg, 256, 0, stream>>>(Xt, nullptr, 1024, WT[4], (const float*)d_in[11], Qb, 1024);
  gemm_kernel<EPI_QKV><<<gg, 256, 0, stream>>>(Xc, nullptr, 1024, WT[5], (const float*)d_in[13], Kb, 1024);
  gemm_kernel<EPI_VT ><<<gg, 256, 0, stream>>>(Xc, nullptr, 1024, WT[6], (const float*)d_in[15], Vtb, 1024);
  attn_kernel<<<1024, 256, 0, stream>>>(Qb, Kb, Vtb, ctx);
  gemm_kernel<EPI_BF16><<<gg, 256, 0, stream>>>(ctx, nullptr, 1024, WT[7], (const float*)d_in[17], ao1, 1024);
  gemm_kernel<EPI_F32><<<gg, 256, 0, stream>>>(Xc, ao1, 1024, WgT, (const float*)d_in[19], gl1, 2048);

  fuse_ln<<<8192, 256, 0, stream>>>(title, content, ao0, ao1, gl0, gl1,
                                    (const float*)d_in[20], (const float*)d_in[21],
                                    (float*)d_out);
}

// Round 2
// 295.745 us; speedup vs baseline: 2.5823x; 2.5823x over previous
//
#include <hip/hip_runtime.h>
#include <cstdint>
#include <cstddef>

typedef unsigned short ushort_t;
typedef unsigned int u32;
typedef __attribute__((ext_vector_type(8))) short bf16x8;
typedef __attribute__((ext_vector_type(4))) float f32x4;
typedef __attribute__((ext_vector_type(4))) unsigned short u16x4;

#define DEV static __device__ __forceinline__

DEV ushort_t f2bf(float f) {
  u32 x = __float_as_uint(f);
  x += 0x7fff + ((x >> 16) & 1);
  return (ushort_t)(x >> 16);
}
DEV float bf2f(ushort_t u) { return __uint_as_float(((u32)u) << 16); }

DEV void gload16(const ushort_t* g, ushort_t* l) {
  __builtin_amdgcn_global_load_lds(
      (const __attribute__((address_space(1))) void*)g,
      (__attribute__((address_space(3))) void*)l, 16, 0, 0);
}

// Dims: B=8, S=512, D=1024, H=16, DH=64, M=B*S=4096 per side.

// ---------------------------------------------------------------------------
__global__ __launch_bounds__(256) void cvt_inputs(
    const float* __restrict__ xa, const float* __restrict__ xb,
    ushort_t* __restrict__ oa, ushort_t* __restrict__ ob) {
  int i = blockIdx.x * 256 + threadIdx.x;
  f32x4 va = ((const f32x4*)xa)[i];
  f32x4 vb = ((const f32x4*)xb)[i];
  u16x4 ua, ub;
#pragma unroll
  for (int j = 0; j < 4; ++j) { ua[j] = f2bf(va[j]); ub[j] = f2bf(vb[j]); }
  ((u16x4*)oa)[i] = ua;
  ((u16x4*)ob)[i] = ub;
}

// ---------------------------------------------------------------------------
// Batched W [K][N] f32 -> Wt [N][K] bf16. z<8: square weights into WTall
// slot z (K=N=1024); z==8: gate weight (K=2048) into WgT.
struct Src9 { const float* p[9]; };

__global__ __launch_bounds__(256) void transpose_cvt(
    Src9 srcs, ushort_t* __restrict__ WTall, ushort_t* __restrict__ WgT) {
  const int z = blockIdx.z;
  const int K = (z == 8) ? 2048 : 1024;
  if (z < 8 && blockIdx.y >= 32) return;
  const float* src = srcs.p[z];
  ushort_t* dst = (z == 8) ? WgT : WTall + ((size_t)z << 20);
  __shared__ float t[32][33];
  int n0 = blockIdx.x << 5, k0 = blockIdx.y << 5;
  int tx = threadIdx.x & 31, ty = threadIdx.x >> 5;
#pragma unroll
  for (int i = 0; i < 4; ++i)
    t[ty + i * 8][tx] = src[(size_t)(k0 + ty + i * 8) * 1024 + n0 + tx];
  __syncthreads();
#pragma unroll
  for (int i = 0; i < 4; ++i)
    dst[(size_t)(n0 + ty + i * 8) * K + k0 + tx] = f2bf(t[tx][ty + i * 8]);
}

// ---------------------------------------------------------------------------
// Unified MFMA GEMM, 128x128 tile, BK=64, 4 waves, global_load_lds staging
// with XOR-swizzled source (rule #21: linear LDS dest + inv-swz source + swz read).
// M_QKV: M=8192 ([Xt;Xc]), N=3072, K=1024. B slot = group*3 + nchunk from WTall.
//        dest slots (4M halfs each) in QKVbuf; slots {1,5} use [b][h][d][s] (VT).
// M_OUT: M=8192 ([ctx0;ctx1]), N=1024, K=1024. B slot = 6+group. dest ao bf16.
// M_GATE:M=8192, N=1024, K=2048. A = [X | ao] concat, B = WgT. dest f32 logits.
enum { M_QKV = 0, M_OUT = 1, M_GATE = 2 };
struct Ptr6 { const float* p[6]; };

template <int MODE>
__global__ __launch_bounds__(256, 3) void gemm_kernel(
    const ushort_t* __restrict__ A1a, const ushort_t* __restrict__ A1b,
    const ushort_t* __restrict__ A2, const ushort_t* __restrict__ Bbase,
    Ptr6 bt, void* __restrict__ out) {
  constexpr int KTOT = (MODE == M_GATE) ? 2048 : 1024;
  __shared__ ushort_t As[128 * 64];
  __shared__ ushort_t Bs[128 * 64];
  const int tid = threadIdx.x;
  const int w = tid >> 6, lane = tid & 63;
  const int g = lane >> 4, c = lane & 15;
  const int wm = (w >> 1) << 6, wn = (w & 1) << 6;
  const int m0 = blockIdx.x << 7, n0 = blockIdx.y << 7;
  const int group = m0 >> 12;
  const int bidx = (MODE == M_QKV) ? group * 3 + (n0 >> 10)
                 : (MODE == M_OUT) ? 6 + group : 0;
  // inverse-swizzled source 16B-slot for staging
  const int csw = (lane & 7) ^ (lane >> 3);

  f32x4 acc[4][4];
#pragma unroll
  for (int i = 0; i < 4; ++i)
#pragma unroll
    for (int j = 0; j < 4; ++j) acc[i][j] = f32x4{0.f, 0.f, 0.f, 0.f};

  for (int k0 = 0; k0 < KTOT; k0 += 64) {
#pragma unroll
    for (int i = 0; i < 4; ++i) {
      const int chunk = (w << 2) + i;             // 0..15
      const int row = (chunk << 3) + (lane >> 3); // 0..127
      // ---- A ----
      const int mg = m0 + row;
      const ushort_t* ap;
      if (MODE == M_GATE && k0 >= 1024) {
        ap = A2 + ((size_t)mg << 10) + (k0 - 1024) + (csw << 3);
      } else {
        const ushort_t* ab = (MODE == M_OUT)
            ? A1a + ((size_t)mg << 10)
            : ((mg >> 12) ? A1b : A1a) + ((size_t)(mg & 4095) << 10);
        ap = ab + k0 + (csw << 3);
      }
      gload16(ap, &As[(size_t)chunk << 9]);
      // ---- B ----
      const ushort_t* bp;
      if (MODE == M_GATE)
        bp = Bbase + ((size_t)(n0 + row) << 11) + k0 + (csw << 3);
      else
        bp = Bbase + ((size_t)bidx << 20) + ((size_t)((n0 & 1023) + row) << 10) +
             k0 + (csw << 3);
      gload16(bp, &Bs[(size_t)chunk << 9]);
    }
    __syncthreads();
    const int cg = c & 7;
#pragma unroll
    for (int ks = 0; ks < 2; ++ks) {
      bf16x8 af[4], bfr[4];
#pragma unroll
      for (int mi = 0; mi < 4; ++mi)
        af[mi] = *(const bf16x8*)&As[((wm + mi * 16 + c) << 6) +
                                     ((((ks << 2) | g) ^ cg) << 3)];
#pragma unroll
      for (int ni = 0; ni < 4; ++ni)
        bfr[ni] = *(const bf16x8*)&Bs[((wn + ni * 16 + c) << 6) +
                                      ((((ks << 2) | g) ^ cg) << 3)];
#pragma unroll
      for (int mi = 0; mi < 4; ++mi)
#pragma unroll
        for (int ni = 0; ni < 4; ++ni)
          acc[mi][ni] = __builtin_amdgcn_mfma_f32_16x16x32_bf16(
              af[mi], bfr[ni], acc[mi][ni], 0, 0, 0);
    }
    __syncthreads();
  }

  // Epilogue. D frag: row(M) = 4*(lane>>4)+reg, col(N) = lane&15.
#pragma unroll
  for (int ni = 0; ni < 4; ++ni) {
    const int n = n0 + wn + ni * 16 + c;
    float bv;
    if (MODE == M_QKV)      bv = bt.p[bidx][n & 1023];
    else if (MODE == M_OUT) bv = bt.p[group][n];
    else                    bv = bt.p[0][n];
#pragma unroll
    for (int mi = 0; mi < 4; ++mi) {
      const int mb = m0 + wm + mi * 16 + (g << 2);
      f32x4 a = acc[mi][ni];
      if (MODE == M_QKV) {
        const int mrow = mb & 4095, b = mrow >> 9, s = mrow & 511;
        const int nloc = n & 1023, h = nloc >> 6, d = nloc & 63;
        ushort_t* base = (ushort_t*)out + ((size_t)bidx << 22);
        if (bidx == 1 || bidx == 5) {  // V^T layout [b][h][d][s]
          u16x4 o;
#pragma unroll
          for (int r = 0; r < 4; ++r) o[r] = f2bf(a[r] + bv);
          *(u16x4*)&base[(((size_t)((b * 16 + h) * 64 + d)) << 9) + s] = o;
        } else {                       // [b][h][s][d]
#pragma unroll
          for (int r = 0; r < 4; ++r)
            base[(((size_t)((b * 16 + h) * 512 + s + r)) << 6) + d] = f2bf(a[r] + bv);
        }
      } else if (MODE == M_OUT) {
#pragma unroll
        for (int r = 0; r < 4; ++r)
          ((ushort_t*)out)[(size_t)(mb + r) * 1024 + n] = f2bf(a[r] + bv);
      } else {
#pragma unroll
        for (int r = 0; r < 4; ++r)
          ((float*)out)[(size_t)(mb + r) * 1024 + n] = a[r] + bv;
      }
    }
  }
}

// ---------------------------------------------------------------------------
// Fused attention, both dirs. Grid 2048 = dir(2) x bh(128) x qtile(8).
// scores^T = mfma(K,Q): lane owns q-column; softmax shift from KL term dropped
// (exact: softmax is shift-invariant per row). PV = mfma(V^T, P).
__global__ __launch_bounds__(256, 2) void attn_kernel(
    const ushort_t* __restrict__ QKV, ushort_t* __restrict__ ctx) {
  const int tid = threadIdx.x, w = tid >> 6, lane = tid & 63;
  const int g = lane >> 4, c = lane & 15;
  const int dir = blockIdx.x >> 10;
  const int bh = (blockIdx.x >> 3) & 127, qt = blockIdx.x & 7;
  const int q0 = (qt << 6) + (w << 4);
  const int qs = dir ? 2 : 3, ks = dir ? 4 : 0, vs = dir ? 5 : 1;
  const ushort_t* Qb = QKV + ((size_t)qs << 22) + ((size_t)bh << 15);
  const ushort_t* Kb = QKV + ((size_t)ks << 22) + ((size_t)bh << 15);
  const ushort_t* Vb = QKV + ((size_t)vs << 22) + ((size_t)bh << 15);

  bf16x8 qf0 = *(const bf16x8*)&Qb[((q0 + c) << 6) + (g << 3)];
  bf16x8 qf1 = *(const bf16x8*)&Qb[((q0 + c) << 6) + 32 + (g << 3)];

  f32x4 s[32];
  float mx = -1e30f;
#pragma unroll
  for (int t = 0; t < 32; ++t) {
    bf16x8 a0 = *(const bf16x8*)&Kb[(((t << 4) + c) << 6) + (g << 3)];
    bf16x8 a1 = *(const bf16x8*)&Kb[(((t << 4) + c) << 6) + 32 + (g << 3)];
    f32x4 z = {0.f, 0.f, 0.f, 0.f};
    z = __builtin_amdgcn_mfma_f32_16x16x32_bf16(a0, qf0, z, 0, 0, 0);
    z = __builtin_amdgcn_mfma_f32_16x16x32_bf16(a1, qf1, z, 0, 0, 0);
    s[t] = z;
    mx = fmaxf(mx, fmaxf(fmaxf(z[0], z[1]), fmaxf(z[2], z[3])));
  }
  mx = fmaxf(mx, __shfl_xor(mx, 16, 64));
  mx = fmaxf(mx, __shfl_xor(mx, 32, 64));
  const float SC = 0.125f;
  float sum = 0.f;
#pragma unroll
  for (int t = 0; t < 32; ++t) {
#pragma unroll
    for (int r = 0; r < 4; ++r) {
      float p = __expf((s[t][r] - mx) * SC);
      s[t][r] = p;
      sum += p;
    }
  }
  sum += __shfl_xor(sum, 16, 64);
  sum += __shfl_xor(sum, 32, 64);
  const float inv = 1.0f / sum;

  f32x4 pacc[4];
#pragma unroll
  for (int dt = 0; dt < 4; ++dt) pacc[dt] = f32x4{0.f, 0.f, 0.f, 0.f};
  const int s1 = ((g & 1) << 5) + c;
  const int s2 = s1 + 16;
  const bool hi = (g >> 1) != 0;
#pragma unroll
  for (int t2 = 0; t2 < 16; ++t2) {
    u32 A0 = ((u32)f2bf(s[2 * t2][1]) << 16) | f2bf(s[2 * t2][0]);
    u32 A1p = ((u32)f2bf(s[2 * t2][3]) << 16) | f2bf(s[2 * t2][2]);
    u32 B0 = ((u32)f2bf(s[2 * t2 + 1][1]) << 16) | f2bf(s[2 * t2 + 1][0]);
    u32 B1 = ((u32)f2bf(s[2 * t2 + 1][3]) << 16) | f2bf(s[2 * t2 + 1][2]);
    u32 xA0 = (u32)__shfl((int)A0, s1, 64), xA1 = (u32)__shfl((int)A1p, s1, 64);
    u32 xB0 = (u32)__shfl((int)B0, s1, 64), xB1 = (u32)__shfl((int)B1, s1, 64);
    u32 yA0 = (u32)__shfl((int)A0, s2, 64), yA1 = (u32)__shfl((int)A1p, s2, 64);
    u32 yB0 = (u32)__shfl((int)B0, s2, 64), yB1 = (u32)__shfl((int)B1, s2, 64);
    union { bf16x8 v; u32 wd[4]; } pb;
    pb.wd[0] = hi ? xB0 : xA0;
    pb.wd[1] = hi ? xB1 : xA1;
    pb.wd[2] = hi ? yB0 : yA0;
    pb.wd[3] = hi ? yB1 : yA1;
#pragma unroll
    for (int dt = 0; dt < 4; ++dt) {
      bf16x8 av = *(const bf16x8*)&Vb[(((dt << 4) + c) << 9) + (t2 << 5) + (g << 3)];
      pacc[dt] = __builtin_amdgcn_mfma_f32_16x16x32_bf16(av, pb.v, pacc[dt], 0, 0, 0);
    }
  }
  const int b = bh >> 4, h = bh & 15;
  size_t obase = ((size_t)dir << 22) + ((size_t)(b * 512 + q0 + c) << 10) + (h << 6);
#pragma unroll
  for (int dt = 0; dt < 4; ++dt) {
    u16x4 o;
#pragma unroll
    for (int r = 0; r < 4; ++r) o[r] = f2bf(pacc[dt][r] * inv);
    *(u16x4*)&ctx[obase + (dt << 4) + (g << 2)] = o;
  }
}

// ---------------------------------------------------------------------------
__global__ __launch_bounds__(256) void fuse_ln(
    const float* __restrict__ xt, const float* __restrict__ xc,
    const ushort_t* __restrict__ ao, const float* __restrict__ gl,
    const float* __restrict__ lng, const float* __restrict__ lnb,
    float* __restrict__ out) {
  const int row = blockIdx.x, dir = row >> 12, r = row & 4095;
  const float* x = (dir ? xc : xt) + ((size_t)r << 10);
  const ushort_t* a = ao + ((size_t)row << 10);
  const float* glr = gl + ((size_t)row << 10);
  float* o = out + ((size_t)row << 10);
  const int t = threadIdx.x, w = t >> 6, lane = t & 63;
  f32x4 xv = ((const f32x4*)x)[t];
  u16x4 av = ((const u16x4*)a)[t];
  f32x4 gv = ((const f32x4*)glr)[t];
  f32x4 f;
  float sm = 0.f, sq = 0.f;
#pragma unroll
  for (int j = 0; j < 4; ++j) {
    float gate = 1.f / (1.f + __expf(-gv[j]));
    float fv = gate * xv[j] + (1.f - gate) * bf2f(av[j]);
    f[j] = fv; sm += fv; sq += fv * fv;
  }
#pragma unroll
  for (int d = 1; d < 64; d <<= 1) {
    sm += __shfl_xor(sm, d, 64);
    sq += __shfl_xor(sq, d, 64);
  }
  __shared__ float ps[8];
  if (lane == 0) { ps[w] = sm; ps[4 + w] = sq; }
  __syncthreads();
  sm = ps[0] + ps[1] + ps[2] + ps[3];
  sq = ps[4] + ps[5] + ps[6] + ps[7];
  const float mu = sm * (1.f / 1024.f);
  const float var = sq * (1.f / 1024.f) - mu * mu;
  const float rstd = rsqrtf(var + 1e-5f);
  f32x4 lg = ((const f32x4*)lng)[t], lb = ((const f32x4*)lnb)[t];
  f32x4 ov;
#pragma unroll
  for (int j = 0; j < 4; ++j) ov[j] = lg[j] * (f[j] - mu) * rstd + lb[j];
  ((f32x4*)o)[t] = ov;
}

// ---------------------------------------------------------------------------
extern "C" void kernel_launch(void* const* d_in, const int* in_sizes, int n_in,
                              void* d_out, int out_size, void* d_ws, size_t ws_size,
                              hipStream_t stream) {
  (void)in_sizes; (void)n_in; (void)out_size; (void)ws_size;
  const float* title = (const float*)d_in[0];
  const float* content = (const float*)d_in[1];

  char* ws = (char*)d_ws;
  const size_t MB = 1u << 20;
  ushort_t* Xt    = (ushort_t*)(ws + 0 * MB);    // 8 MB bf16 [4096][1024]
  ushort_t* Xc    = (ushort_t*)(ws + 8 * MB);    // 8 MB
  ushort_t* WTall = (ushort_t*)(ws + 16 * MB);   // 16 MB: 8 slots [1024][1024]
  ushort_t* WgT   = (ushort_t*)(ws + 32 * MB);   // 4 MB [1024][2048]
  ushort_t* QKV   = (ushort_t*)(ws + 36 * MB);   // 48 MB: 6 slots of 8 MB
  ushort_t* ao    = (ushort_t*)(ws + 36 * MB);   // aliases QKV slots 0-1 (dead)
  float*    gl    = (float*)  (ws + 52 * MB);    // 32 MB, aliases slots 2-5 (dead)
  ushort_t* ctx   = (ushort_t*)(ws + 84 * MB);   // 16 MB [2][4096][1024]
  // total footprint 100 MB

  cvt_inputs<<<4096, 256, 0, stream>>>(title, content, Xt, Xc);

  // weight slot order: {t2c_wk,t2c_wv,c2t_wq, t2c_wq,c2t_wk,c2t_wv, t2c_wo,c2t_wo}
  Src9 srcs;
  srcs.p[0] = (const float*)d_in[4];  srcs.p[1] = (const float*)d_in[6];
  srcs.p[2] = (const float*)d_in[10]; srcs.p[3] = (const float*)d_in[2];
  srcs.p[4] = (const float*)d_in[12]; srcs.p[5] = (const float*)d_in[14];
  srcs.p[6] = (const float*)d_in[8];  srcs.p[7] = (const float*)d_in[16];
  srcs.p[8] = (const float*)d_in[18];
  transpose_cvt<<<dim3(32, 64, 9), 256, 0, stream>>>(srcs, WTall, WgT);

  // fused QKV: group0 rows = title, group1 = content
  Ptr6 bq;
  bq.p[0] = (const float*)d_in[5];  bq.p[1] = (const float*)d_in[7];
  bq.p[2] = (const float*)d_in[11]; bq.p[3] = (const float*)d_in[3];
  bq.p[4] = (const float*)d_in[13]; bq.p[5] = (const float*)d_in[15];
  gemm_kernel<M_QKV><<<dim3(64, 24), 256, 0, stream>>>(Xt, Xc, nullptr, WTall, bq, QKV);

  attn_kernel<<<2048, 256, 0, stream>>>(QKV, ctx);

  Ptr6 bo;
  bo.p[0] = (const float*)d_in[9]; bo.p[1] = (const float*)d_in[17];
  for (int i = 2; i < 6; ++i) bo.p[i] = nullptr;
  gemm_kernel<M_OUT><<<dim3(64, 8), 256, 0, stream>>>(ctx, nullptr, nullptr, WTall, bo, ao);

  Ptr6 bg;
  bg.p[0] = (const float*)d_in[19];
  for (int i = 1; i < 6; ++i) bg.p[i] = nullptr;
  gemm_kernel<M_GATE><<<dim3(64, 8), 256, 0, stream>>>(Xt, Xc, ao, WgT, bg, gl);

  fuse_ln<<<8192, 256, 0, stream>>>(title, content, ao, gl,
                                    (const float*)d_in[20], (const float*)d_in[21],
                                    (float*)d_out);
}

// Round 3
// 218.432 us; speedup vs baseline: 3.4963x; 1.3539x over previous
//
#include <hip/hip_runtime.h>
#include <cstdint>
#include <cstddef>

typedef unsigned short ushort_t;
typedef unsigned int u32;
typedef __attribute__((ext_vector_type(8))) short bf16x8;
typedef __attribute__((ext_vector_type(4))) float f32x4;
typedef __attribute__((ext_vector_type(4))) unsigned short u16x4;

#define DEV static __device__ __forceinline__

DEV ushort_t f2bf(float f) {
  u32 x = __float_as_uint(f);
  x += 0x7fff + ((x >> 16) & 1);
  return (ushort_t)(x >> 16);
}
DEV float bf2f(ushort_t u) { return __uint_as_float(((u32)u) << 16); }

DEV void gload16(const ushort_t* g, ushort_t* l) {
  __builtin_amdgcn_global_load_lds(
      (const __attribute__((address_space(1))) void*)g,
      (__attribute__((address_space(3))) void*)l, 16, 0, 0);
}

// Dims: B=8, S=512, D=1024, H=16, DH=64, M=B*S=4096 per side.

// ---------------------------------------------------------------------------
__global__ __launch_bounds__(256) void cvt_inputs(
    const float* __restrict__ xa, const float* __restrict__ xb,
    ushort_t* __restrict__ oa, ushort_t* __restrict__ ob) {
  int i = blockIdx.x * 256 + threadIdx.x;
  f32x4 va = ((const f32x4*)xa)[i];
  f32x4 vb = ((const f32x4*)xb)[i];
  u16x4 ua, ub;
#pragma unroll
  for (int j = 0; j < 4; ++j) { ua[j] = f2bf(va[j]); ub[j] = f2bf(vb[j]); }
  ((u16x4*)oa)[i] = ua;
  ((u16x4*)ob)[i] = ub;
}

// ---------------------------------------------------------------------------
struct Src9 { const float* p[9]; };

__global__ __launch_bounds__(256) void transpose_cvt(
    Src9 srcs, ushort_t* __restrict__ WTall, ushort_t* __restrict__ WgT) {
  const int z = blockIdx.z;
  const int K = (z == 8) ? 2048 : 1024;
  if (z < 8 && blockIdx.y >= 32) return;
  const float* src = srcs.p[z];
  ushort_t* dst = (z == 8) ? WgT : WTall + ((size_t)z << 20);
  __shared__ float t[32][33];
  int n0 = blockIdx.x << 5, k0 = blockIdx.y << 5;
  int tx = threadIdx.x & 31, ty = threadIdx.x >> 5;
#pragma unroll
  for (int i = 0; i < 4; ++i)
    t[ty + i * 8][tx] = src[(size_t)(k0 + ty + i * 8) * 1024 + n0 + tx];
  __syncthreads();
#pragma unroll
  for (int i = 0; i < 4; ++i)
    dst[(size_t)(n0 + ty + i * 8) * K + k0 + tx] = f2bf(t[tx][ty + i * 8]);
}

// ---------------------------------------------------------------------------
// Unified MFMA GEMM, 128x128 tile, BK=64, 4 waves, global_load_lds staging
// with XOR-swizzled source (linear LDS dest + inv-swz source + swz read).
enum { M_QKV = 0, M_OUT = 1, M_GATE = 2 };
struct Ptr6 { const float* p[6]; };

template <int MODE>
__global__ __launch_bounds__(256, 3) void gemm_kernel(
    const ushort_t* __restrict__ A1a, const ushort_t* __restrict__ A1b,
    const ushort_t* __restrict__ A2, const ushort_t* __restrict__ Bbase,
    Ptr6 bt, void* __restrict__ out) {
  constexpr int KTOT = (MODE == M_GATE) ? 2048 : 1024;
  __shared__ ushort_t As[128 * 64];
  __shared__ ushort_t Bs[128 * 64];
  const int tid = threadIdx.x;
  const int w = tid >> 6, lane = tid & 63;
  const int g = lane >> 4, c = lane & 15;
  const int wm = (w >> 1) << 6, wn = (w & 1) << 6;
  const int m0 = blockIdx.x << 7, n0 = blockIdx.y << 7;
  const int group = m0 >> 12;
  const int bidx = (MODE == M_QKV) ? group * 3 + (n0 >> 10)
                 : (MODE == M_OUT) ? 6 + group : 0;
  const int csw = (lane & 7) ^ (lane >> 3);

  f32x4 acc[4][4];
#pragma unroll
  for (int i = 0; i < 4; ++i)
#pragma unroll
    for (int j = 0; j < 4; ++j) acc[i][j] = f32x4{0.f, 0.f, 0.f, 0.f};

  for (int k0 = 0; k0 < KTOT; k0 += 64) {
#pragma unroll
    for (int i = 0; i < 4; ++i) {
      const int chunk = (w << 2) + i;
      const int row = (chunk << 3) + (lane >> 3);
      const int mg = m0 + row;
      const ushort_t* ap;
      if (MODE == M_GATE && k0 >= 1024) {
        ap = A2 + ((size_t)mg << 10) + (k0 - 1024) + (csw << 3);
      } else {
        const ushort_t* ab = (MODE == M_OUT)
            ? A1a + ((size_t)mg << 10)
            : ((mg >> 12) ? A1b : A1a) + ((size_t)(mg & 4095) << 10);
        ap = ab + k0 + (csw << 3);
      }
      gload16(ap, &As[(size_t)chunk << 9]);
      const ushort_t* bp;
      if (MODE == M_GATE)
        bp = Bbase + ((size_t)(n0 + row) << 11) + k0 + (csw << 3);
      else
        bp = Bbase + ((size_t)bidx << 20) + ((size_t)((n0 & 1023) + row) << 10) +
             k0 + (csw << 3);
      gload16(bp, &Bs[(size_t)chunk << 9]);
    }
    __syncthreads();
    const int cg = c & 7;
#pragma unroll
    for (int ks = 0; ks < 2; ++ks) {
      bf16x8 af[4], bfr[4];
#pragma unroll
      for (int mi = 0; mi < 4; ++mi)
        af[mi] = *(const bf16x8*)&As[((wm + mi * 16 + c) << 6) +
                                     ((((ks << 2) | g) ^ cg) << 3)];
#pragma unroll
      for (int ni = 0; ni < 4; ++ni)
        bfr[ni] = *(const bf16x8*)&Bs[((wn + ni * 16 + c) << 6) +
                                      ((((ks << 2) | g) ^ cg) << 3)];
#pragma unroll
      for (int mi = 0; mi < 4; ++mi)
#pragma unroll
        for (int ni = 0; ni < 4; ++ni)
          acc[mi][ni] = __builtin_amdgcn_mfma_f32_16x16x32_bf16(
              af[mi], bfr[ni], acc[mi][ni], 0, 0, 0);
    }
    __syncthreads();
  }

#pragma unroll
  for (int ni = 0; ni < 4; ++ni) {
    const int n = n0 + wn + ni * 16 + c;
    float bv;
    if (MODE == M_QKV)      bv = bt.p[bidx][n & 1023];
    else if (MODE == M_OUT) bv = bt.p[group][n];
    else                    bv = bt.p[0][n];
#pragma unroll
    for (int mi = 0; mi < 4; ++mi) {
      const int mb = m0 + wm + mi * 16 + (g << 2);
      f32x4 a = acc[mi][ni];
      if (MODE == M_QKV) {
        const int mrow = mb & 4095, b = mrow >> 9, s = mrow & 511;
        const int nloc = n & 1023, h = nloc >> 6, d = nloc & 63;
        ushort_t* base = (ushort_t*)out + ((size_t)bidx << 22);
        if (bidx == 1 || bidx == 5) {  // V^T layout [b][h][d][s]
          u16x4 o;
#pragma unroll
          for (int r = 0; r < 4; ++r) o[r] = f2bf(a[r] + bv);
          *(u16x4*)&base[(((size_t)((b * 16 + h) * 64 + d)) << 9) + s] = o;
        } else {                       // [b][h][s][d]
#pragma unroll
          for (int r = 0; r < 4; ++r)
            base[(((size_t)((b * 16 + h) * 512 + s + r)) << 6) + d] = f2bf(a[r] + bv);
        }
      } else if (MODE == M_OUT) {
#pragma unroll
        for (int r = 0; r < 4; ++r)
          ((ushort_t*)out)[(size_t)(mb + r) * 1024 + n] = f2bf(a[r] + bv);
      } else {
#pragma unroll
        for (int r = 0; r < 4; ++r)
          ((float*)out)[(size_t)(mb + r) * 1024 + n] = a[r] + bv;
      }
    }
  }
}

// ---------------------------------------------------------------------------
// Fused attention, both dirs. 2048 blocks (XCD-swizzled so the 8 q-tiles of a
// bh share one XCD L2). K (score phase) and V (PV phase) staged via 2x16KB
// double-buffered LDS with global_load_lds + XOR swizzle; 4 waves share them.
// scores^T = mfma(K,Q); KL row-shift dropped (softmax shift-invariant).
__global__ __launch_bounds__(256, 2) void attn_kernel(
    const ushort_t* __restrict__ QKV, ushort_t* __restrict__ ctx) {
  __shared__ ushort_t kv[2][8192];  // 2 x 16 KB
  const int tid = threadIdx.x, w = tid >> 6, lane = tid & 63;
  const int g = lane >> 4, c = lane & 15, c7 = c & 7;
  const int bid = (int)blockIdx.x;
  const int wid = (bid & 7) * 256 + (bid >> 3);  // XCD-contiguous work ids
  const int dir = wid >> 10;
  const int bh = (wid >> 3) & 127, qt = wid & 7;
  const int q0 = (qt << 6) + (w << 4);
  const int qs = dir ? 2 : 3, ks = dir ? 4 : 0, vs = dir ? 5 : 1;
  const ushort_t* Qb = QKV + ((size_t)qs << 22) + ((size_t)bh << 15);
  const ushort_t* Kb = QKV + ((size_t)ks << 22) + ((size_t)bh << 15);
  const ushort_t* Vb = QKV + ((size_t)vs << 22) + ((size_t)bh << 15);

  // K chunk: 128 k-rows x 64 d. LDS linear dest; source col-slot inv-swizzled.
  auto stageK = [&](int b, int kc) {
#pragma unroll
    for (int i = 0; i < 4; ++i) {
      int idx = tid + (i << 8);
      int r = idx >> 3, sl = idx & 7;
      int cs = sl ^ (r & 7);
      gload16(Kb + (((size_t)((kc << 7) + r)) << 6) + (cs << 3), &kv[b][idx << 3]);
    }
  };
  // V chunk: 64 d-rows x 128 s-cols from V^T [64][512].
  auto stageV = [&](int b, int vc) {
#pragma unroll
    for (int i = 0; i < 4; ++i) {
      int idx = tid + (i << 8);
      int r = idx >> 4, sl = idx & 15;
      int cs = sl ^ (r & 15);
      gload16(Vb + ((size_t)r << 9) + (vc << 7) + (cs << 3), &kv[b][idx << 3]);
    }
  };

  bf16x8 qf0 = *(const bf16x8*)&Qb[((q0 + c) << 6) + (g << 3)];
  bf16x8 qf1 = *(const bf16x8*)&Qb[((q0 + c) << 6) + 32 + (g << 3)];

  f32x4 s[32];  // scores^T: rows kk, col q = q0 + c
  float mx = -1e30f;
  int buf = 0;
  stageK(0, 0);
  __syncthreads();
#pragma unroll
  for (int kc = 0; kc < 4; ++kc) {
    if (kc < 3) stageK(buf ^ 1, kc + 1);
    __builtin_amdgcn_s_setprio(1);
#pragma unroll
    for (int t = 0; t < 8; ++t) {
      const ushort_t* base = &kv[buf][((t << 4) + c) << 6];
      bf16x8 a0 = *(const bf16x8*)&base[(g ^ c7) << 3];
      bf16x8 a1 = *(const bf16x8*)&base[((4 | g) ^ c7) << 3];
      f32x4 z = {0.f, 0.f, 0.f, 0.f};
      z = __builtin_amdgcn_mfma_f32_16x16x32_bf16(a0, qf0, z, 0, 0, 0);
      z = __builtin_amdgcn_mfma_f32_16x16x32_bf16(a1, qf1, z, 0, 0, 0);
      s[kc * 8 + t] = z;
      mx = fmaxf(mx, fmaxf(fmaxf(z[0], z[1]), fmaxf(z[2], z[3])));
    }
    __builtin_amdgcn_s_setprio(0);
    __syncthreads();
    buf ^= 1;
  }
  // buf == 0 again. Issue V chunk 0 now; softmax (register-only) hides it.
  stageV(0, 0);
  buf = 0;

  mx = fmaxf(mx, __shfl_xor(mx, 16, 64));
  mx = fmaxf(mx, __shfl_xor(mx, 32, 64));
  const float SC = 0.125f;
  float sum = 0.f;
#pragma unroll
  for (int t = 0; t < 32; ++t) {
#pragma unroll
    for (int r = 0; r < 4; ++r) {
      float p = __expf((s[t][r] - mx) * SC);
      s[t][r] = p;
      sum += p;
    }
  }
  sum += __shfl_xor(sum, 16, 64);
  sum += __shfl_xor(sum, 32, 64);
  const float inv = 1.0f / sum;

  f32x4 pacc[4];
#pragma unroll
  for (int dt = 0; dt < 4; ++dt) pacc[dt] = f32x4{0.f, 0.f, 0.f, 0.f};
  const int s1 = ((g & 1) << 5) + c;
  const int s2 = s1 + 16;
  const bool hi = (g >> 1) != 0;
  __syncthreads();
#pragma unroll
  for (int vc = 0; vc < 4; ++vc) {
    if (vc < 3) stageV(buf ^ 1, vc + 1);
#pragma unroll
    for (int t2l = 0; t2l < 4; ++t2l) {
      const int t2 = (vc << 2) + t2l;
      u32 A0 = ((u32)f2bf(s[2 * t2][1]) << 16) | f2bf(s[2 * t2][0]);
      u32 A1p = ((u32)f2bf(s[2 * t2][3]) << 16) | f2bf(s[2 * t2][2]);
      u32 B0 = ((u32)f2bf(s[2 * t2 + 1][1]) << 16) | f2bf(s[2 * t2 + 1][0]);
      u32 B1 = ((u32)f2bf(s[2 * t2 + 1][3]) << 16) | f2bf(s[2 * t2 + 1][2]);
      u32 xA0 = (u32)__shfl((int)A0, s1, 64), xA1 = (u32)__shfl((int)A1p, s1, 64);
      u32 xB0 = (u32)__shfl((int)B0, s1, 64), xB1 = (u32)__shfl((int)B1, s1, 64);
      u32 yA0 = (u32)__shfl((int)A0, s2, 64), yA1 = (u32)__shfl((int)A1p, s2, 64);
      u32 yB0 = (u32)__shfl((int)B0, s2, 64), yB1 = (u32)__shfl((int)B1, s2, 64);
      union { bf16x8 v; u32 wd[4]; } pb;
      pb.wd[0] = hi ? xB0 : xA0;
      pb.wd[1] = hi ? xB1 : xA1;
      pb.wd[2] = hi ? yB0 : yA0;
      pb.wd[3] = hi ? yB1 : yA1;
      __builtin_amdgcn_s_setprio(1);
#pragma unroll
      for (int dt = 0; dt < 4; ++dt) {
        bf16x8 av = *(const bf16x8*)
            &kv[buf][(((dt << 4) + c) << 7) + ((((t2l << 2) | g) ^ c) << 3)];
        pacc[dt] = __builtin_amdgcn_mfma_f32_16x16x32_bf16(av, pb.v, pacc[dt], 0, 0, 0);
      }
      __builtin_amdgcn_s_setprio(0);
    }
    __syncthreads();
    buf ^= 1;
  }

  const int b = bh >> 4, h = bh & 15;
  size_t obase = ((size_t)dir << 22) + ((size_t)(b * 512 + q0 + c) << 10) + (h << 6);
#pragma unroll
  for (int dt = 0; dt < 4; ++dt) {
    u16x4 o;
#pragma unroll
    for (int r = 0; r < 4; ++r) o[r] = f2bf(pacc[dt][r] * inv);
    *(u16x4*)&ctx[obase + (dt << 4) + (g << 2)] = o;
  }
}

// ---------------------------------------------------------------------------
__global__ __launch_bounds__(256) void fuse_ln(
    const float* __restrict__ xt, const float* __restrict__ xc,
    const ushort_t* __restrict__ ao, const float* __restrict__ gl,
    const float* __restrict__ lng, const float* __restrict__ lnb,
    float* __restrict__ out) {
  const int row = blockIdx.x, dir = row >> 12, r = row & 4095;
  const float* x = (dir ? xc : xt) + ((size_t)r << 10);
  const ushort_t* a = ao + ((size_t)row << 10);
  const float* glr = gl + ((size_t)row << 10);
  float* o = out + ((size_t)row << 10);
  const int t = threadIdx.x, w = t >> 6, lane = t & 63;
  f32x4 xv = ((const f32x4*)x)[t];
  u16x4 av = ((const u16x4*)a)[t];
  f32x4 gv = ((const f32x4*)glr)[t];
  f32x4 f;
  float sm = 0.f, sq = 0.f;
#pragma unroll
  for (int j = 0; j < 4; ++j) {
    float gate = 1.f / (1.f + __expf(-gv[j]));
    float fv = gate * xv[j] + (1.f - gate) * bf2f(av[j]);
    f[j] = fv; sm += fv; sq += fv * fv;
  }
#pragma unroll
  for (int d = 1; d < 64; d <<= 1) {
    sm += __shfl_xor(sm, d, 64);
    sq += __shfl_xor(sq, d, 64);
  }
  __shared__ float ps[8];
  if (lane == 0) { ps[w] = sm; ps[4 + w] = sq; }
  __syncthreads();
  sm = ps[0] + ps[1] + ps[2] + ps[3];
  sq = ps[4] + ps[5] + ps[6] + ps[7];
  const float mu = sm * (1.f / 1024.f);
  const float var = sq * (1.f / 1024.f) - mu * mu;
  const float rstd = rsqrtf(var + 1e-5f);
  f32x4 lg = ((const f32x4*)lng)[t], lb = ((const f32x4*)lnb)[t];
  f32x4 ov;
#pragma unroll
  for (int j = 0; j < 4; ++j) ov[j] = lg[j] * (f[j] - mu) * rstd + lb[j];
  ((f32x4*)o)[t] = ov;
}

// ---------------------------------------------------------------------------
extern "C" void kernel_launch(void* const* d_in, const int* in_sizes, int n_in,
                              void* d_out, int out_size, void* d_ws, size_t ws_size,
                              hipStream_t stream) {
  (void)in_sizes; (void)n_in; (void)out_size; (void)ws_size;
  const float* title = (const float*)d_in[0];
  const float* content = (const float*)d_in[1];

  char* ws = (char*)d_ws;
  const size_t MB = 1u << 20;
  ushort_t* Xt    = (ushort_t*)(ws + 0 * MB);    // 8 MB bf16 [4096][1024]
  ushort_t* Xc    = (ushort_t*)(ws + 8 * MB);    // 8 MB
  ushort_t* WTall = (ushort_t*)(ws + 16 * MB);   // 16 MB: 8 slots [1024][1024]
  ushort_t* WgT   = (ushort_t*)(ws + 32 * MB);   // 4 MB [1024][2048]
  ushort_t* QKV   = (ushort_t*)(ws + 36 * MB);   // 48 MB: 6 slots of 8 MB
  ushort_t* ao    = (ushort_t*)(ws + 36 * MB);   // aliases QKV slots 0-1 (dead)
  float*    gl    = (float*)  (ws + 52 * MB);    // 32 MB, aliases slots 2-5 (dead)
  ushort_t* ctx   = (ushort_t*)(ws + 84 * MB);   // 16 MB [2][4096][1024]

  cvt_inputs<<<4096, 256, 0, stream>>>(title, content, Xt, Xc);

  // weight slot order: {t2c_wk,t2c_wv,c2t_wq, t2c_wq,c2t_wk,c2t_wv, t2c_wo,c2t_wo}
  Src9 srcs;
  srcs.p[0] = (const float*)d_in[4];  srcs.p[1] = (const float*)d_in[6];
  srcs.p[2] = (const float*)d_in[10]; srcs.p[3] = (const float*)d_in[2];
  srcs.p[4] = (const float*)d_in[12]; srcs.p[5] = (const float*)d_in[14];
  srcs.p[6] = (const float*)d_in[8];  srcs.p[7] = (const float*)d_in[16];
  srcs.p[8] = (const float*)d_in[18];
  transpose_cvt<<<dim3(32, 64, 9), 256, 0, stream>>>(srcs, WTall, WgT);

  Ptr6 bq;
  bq.p[0] = (const float*)d_in[5];  bq.p[1] = (const float*)d_in[7];
  bq.p[2] = (const float*)d_in[11]; bq.p[3] = (const float*)d_in[3];
  bq.p[4] = (const float*)d_in[13]; bq.p[5] = (const float*)d_in[15];
  gemm_kernel<M_QKV><<<dim3(64, 24), 256, 0, stream>>>(Xt, Xc, nullptr, WTall, bq, QKV);

  attn_kernel<<<2048, 256, 0, stream>>>(QKV, ctx);

  Ptr6 bo;
  bo.p[0] = (const float*)d_in[9]; bo.p[1] = (const float*)d_in[17];
  for (int i = 2; i < 6; ++i) bo.p[i] = nullptr;
  gemm_kernel<M_OUT><<<dim3(64, 8), 256, 0, stream>>>(ctx, nullptr, nullptr, WTall, bo, ao);

  Ptr6 bg;
  bg.p[0] = (const float*)d_in[19];
  for (int i = 1; i < 6; ++i) bg.p[i] = nullptr;
  gemm_kernel<M_GATE><<<dim3(64, 8), 256, 0, stream>>>(Xt, Xc, ao, WgT, bg, gl);

  fuse_ln<<<8192, 256, 0, stream>>>(title, content, ao, gl,
                                    (const float*)d_in[20], (const float*)d_in[21],
                                    (float*)d_out);
}